// Round 3
// baseline (642.478 us; speedup 1.0000x reference)
//
#include <hip/hip_runtime.h>

#define S_TOK 4096
#define DMODEL 1024
#define HDIM 4096
#define NEXP 8
#define CAPACITY 1280

struct TokenRoute { int e1, p1, e2, p2; float w1, w2; };

typedef __bf16 bf16x8 __attribute__((ext_vector_type(8)));
typedef float f32x4 __attribute__((ext_vector_type(4)));
typedef unsigned short ushort8v __attribute__((ext_vector_type(8)));

__device__ __forceinline__ unsigned short f2bf(float f) {
    unsigned int u = __float_as_uint(f);
    unsigned int r = 0x7fffu + ((u >> 16) & 1u);
    return (unsigned short)((u + r) >> 16);
}
__device__ __forceinline__ float bf2f(unsigned short b) {
    return __uint_as_float(((unsigned int)b) << 16);
}

__device__ __forceinline__ void gload16(const void* gsrc, void* ldst) {
    __builtin_amdgcn_global_load_lds(
        (const __attribute__((address_space(1))) unsigned int*)gsrc,
        (__attribute__((address_space(3))) unsigned int*)ldst, 16, 0, 0);
}

template <int N> __device__ __forceinline__ void wait_vmcnt() {
    if constexpr (N == 0) asm volatile("s_waitcnt vmcnt(0)" ::: "memory");
    else if constexpr (N == 6) asm volatile("s_waitcnt vmcnt(6)" ::: "memory");
    else if constexpr (N == 8) asm volatile("s_waitcnt vmcnt(8)" ::: "memory");
}

__device__ __forceinline__ float gelu_f(float x) {
    float u = x * (0.7978845608028654f + 0.0356774081363f * x * x);
    return x / (1.0f + __expf(-2.0f * u));   // == 0.5x(1+tanh(u))
}

// ---------------- transpose + fp32->bf16: src [E][R][C] f32 -> dst [E][C][R] bf16
__global__ void transpose_cvt(const float* __restrict__ src, unsigned short* __restrict__ dst,
                              int R, int C) {
    __shared__ unsigned short t[64][66];   // 66: 33-dword row stride, odd mod 32
    size_t eoff = (size_t)blockIdx.z * R * C;
    int r0 = blockIdx.y * 64, c0 = blockIdx.x * 64, tid = threadIdx.x;
    int rr = tid >> 4, cq = (tid & 15) * 4;
#pragma unroll
    for (int p = 0; p < 4; ++p) {
        int row = p * 16 + rr;
        float4 v = *(const float4*)(src + eoff + (size_t)(r0 + row) * C + c0 + cq);
        t[row][cq + 0] = f2bf(v.x); t[row][cq + 1] = f2bf(v.y);
        t[row][cq + 2] = f2bf(v.z); t[row][cq + 3] = f2bf(v.w);
    }
    __syncthreads();
    int k0 = (tid & 7) * 8;
#pragma unroll
    for (int pp = 0; pp < 2; ++pp) {
        int oc = pp * 32 + (tid >> 3);
        ushort8v o;
#pragma unroll
        for (int x = 0; x < 8; ++x) o[x] = t[k0 + x][oc];
        *(ushort8v*)(dst + eoff + (size_t)(c0 + oc) * R + r0 + k0) = o;
    }
}

// ---------------- gating: logits, softmax, top-2. One 64-lane block per token.
__global__ void gate_kernel(const float* __restrict__ tokens, const float* __restrict__ gw,
                            float* __restrict__ gates, TokenRoute* __restrict__ route) {
    int s = blockIdx.x, l = threadIdx.x;
    const float* x = tokens + (size_t)s * DMODEL;
    float p[NEXP];
#pragma unroll
    for (int e = 0; e < NEXP; ++e) p[e] = 0.f;
#pragma unroll
    for (int it = 0; it < 4; ++it) {
        int i = (it * 64 + l) * 4;
        float4 v = *(const float4*)(x + i);
#pragma unroll
        for (int e = 0; e < NEXP; ++e) {
            float4 g = *(const float4*)(gw + e * DMODEL + i);
            p[e] += v.x * g.x + v.y * g.y + v.z * g.z + v.w * g.w;
        }
    }
#pragma unroll
    for (int e = 0; e < NEXP; ++e) {
        float v = p[e];
        v += __shfl_xor(v, 32); v += __shfl_xor(v, 16); v += __shfl_xor(v, 8);
        v += __shfl_xor(v, 4);  v += __shfl_xor(v, 2);  v += __shfl_xor(v, 1);
        p[e] = v;
    }
    int e1 = 0; float b1v = p[0];
#pragma unroll
    for (int e = 1; e < NEXP; ++e) if (p[e] > b1v) { b1v = p[e]; e1 = e; }
    int e2 = -1; float b2v = -3.0e38f;
#pragma unroll
    for (int e = 0; e < NEXP; ++e) if (e != e1 && p[e] > b2v) { b2v = p[e]; e2 = e; }
    float mx = p[0];
#pragma unroll
    for (int e = 1; e < NEXP; ++e) mx = fmaxf(mx, p[e]);
    float sum = 0.f;
#pragma unroll
    for (int e = 0; e < NEXP; ++e) { p[e] = __expf(p[e] - mx); sum += p[e]; }
    float inv = 1.0f / sum;
#pragma unroll
    for (int e = 0; e < NEXP; ++e) p[e] *= inv;
    float g1 = __expf(b1v - mx) * inv;
    float g2 = __expf(b2v - mx) * inv;
    if (l == 0) {
        float* gp = gates + (size_t)s * NEXP;
#pragma unroll
        for (int e = 0; e < NEXP; ++e) gp[e] = p[e];
        TokenRoute r; r.e1 = e1; r.p1 = 0; r.e2 = e2; r.p2 = 0; r.w1 = g1; r.w2 = g2;
        route[s] = r;
    }
}

// ---------------- routing scan (hierarchical, packed 8x16-bit counters in 2x u64)
__device__ __forceinline__ unsigned ext16(unsigned long long lo, unsigned long long hi, int e) {
    unsigned long long q = (e < 4) ? lo : hi;
    return (unsigned)((q >> ((e & 3) * 16)) & 0xFFFFULL);
}

__global__ __launch_bounds__(1024)
void route_scan(TokenRoute* __restrict__ route, const float* __restrict__ gates,
                int* __restrict__ cnt, float* __restrict__ laux_out) {
    __shared__ unsigned long long wt[16][4];
    __shared__ float fsum[16][NEXP];
    int t = threadIdx.x, wid = t >> 6, ln = t & 63;
    TokenRoute tr[4];
    unsigned long long own[4] = {0, 0, 0, 0};
#pragma unroll
    for (int j = 0; j < 4; ++j) {
        tr[j] = route[t * 4 + j];
        int e1 = tr[j].e1, e2 = tr[j].e2;
        if (e1 < 4) own[0] += 1ULL << (e1 * 16); else own[1] += 1ULL << ((e1 - 4) * 16);
        if (e2 < 4) own[2] += 1ULL << (e2 * 16); else own[3] += 1ULL << ((e2 - 4) * 16);
    }
    unsigned long long inc[4] = {own[0], own[1], own[2], own[3]};
#pragma unroll
    for (int off = 1; off < 64; off <<= 1) {
#pragma unroll
        for (int q = 0; q < 4; ++q) {
            unsigned long long v = __shfl_up(inc[q], off);
            if (ln >= off) inc[q] += v;
        }
    }
    if (ln == 63) {
#pragma unroll
        for (int q = 0; q < 4; ++q) wt[wid][q] = inc[q];
    }
    __syncthreads();
    unsigned long long woff[4] = {0, 0, 0, 0}, tot[4] = {0, 0, 0, 0};
    for (int w = 0; w < 16; ++w) {
#pragma unroll
        for (int q = 0; q < 4; ++q) {
            unsigned long long v = wt[w][q];
            tot[q] += v;
            if (w < wid) woff[q] += v;
        }
    }
    unsigned long long ex[4];
#pragma unroll
    for (int q = 0; q < 4; ++q) ex[q] = woff[q] + inc[q] - own[q];

    // gate sums for l_aux
    float gs[NEXP];
#pragma unroll
    for (int e = 0; e < NEXP; ++e) gs[e] = 0.f;
#pragma unroll
    for (int j = 0; j < 4; ++j) {
        const float* gp = gates + (size_t)(t * 4 + j) * NEXP;
#pragma unroll
        for (int e = 0; e < NEXP; ++e) gs[e] += gp[e];
    }
#pragma unroll
    for (int e = 0; e < NEXP; ++e) {
        float v = gs[e];
        v += __shfl_xor(v, 32); v += __shfl_xor(v, 16); v += __shfl_xor(v, 8);
        v += __shfl_xor(v, 4);  v += __shfl_xor(v, 2);  v += __shfl_xor(v, 1);
        gs[e] = v;
    }
    if (ln == 0) {
#pragma unroll
        for (int e = 0; e < NEXP; ++e) fsum[wid][e] = gs[e];
    }
    __syncthreads();
    if (t == 0) {
        float laux = 0.f;
#pragma unroll
        for (int e = 0; e < NEXP; ++e) {
            float m = 0.f;
            for (int w = 0; w < 16; ++w) m += fsum[w][e];
            unsigned t1 = ext16(tot[0], tot[1], e);
            unsigned t2 = ext16(tot[2], tot[3], e);
            laux += (m / (float)S_TOK) * ((float)t1 / (float)S_TOK);
            int c = (int)(t1 + t2);
            cnt[e] = c < CAPACITY ? c : CAPACITY;
        }
        *laux_out = laux * (float)NEXP;
    }
    unsigned long long r1lo = ex[0], r1hi = ex[1], r2lo = ex[2], r2hi = ex[3];
#pragma unroll
    for (int j = 0; j < 4; ++j) {
        int e1 = tr[j].e1, e2 = tr[j].e2;
        unsigned loc1 = ext16(r1lo, r1hi, e1);
        if (e1 < 4) r1lo += 1ULL << (e1 * 16); else r1hi += 1ULL << ((e1 - 4) * 16);
        unsigned loc2 = ext16(r2lo, r2hi, e2) + ext16(tot[0], tot[1], e2);
        if (e2 < 4) r2lo += 1ULL << (e2 * 16); else r2hi += 1ULL << ((e2 - 4) * 16);
        bool k1 = loc1 < CAPACITY, k2 = loc2 < CAPACITY;
        float G1 = k1 ? tr[j].w1 : 0.f;
        float G2 = k2 ? tr[j].w2 : 0.f;
        float denom = fmaxf(G1 + G2, 1.1920929e-07f);
        TokenRoute r;
        r.e1 = e1; r.p1 = k1 ? (int)loc1 : -1;
        r.e2 = e2; r.p2 = k2 ? (int)loc2 : -1;
        r.w1 = G1 / denom; r.w2 = G2 / denom;
        route[t * 4 + j] = r;
    }
}

// ---------------- dispatch scatter: tokens -> disp[e][pos][:] (bf16)
__global__ void dispatch_scatter(const float* __restrict__ tokens, const TokenRoute* __restrict__ route,
                                 unsigned short* __restrict__ disp) {
    int s = blockIdx.x, l = threadIdx.x;
    TokenRoute r = route[s];
    const float* x = tokens + (size_t)s * DMODEL;
    ushort4 vals[4];
#pragma unroll
    for (int q = 0; q < 4; ++q) {
        float4 v = *(const float4*)(x + (q * 64 + l) * 4);
        vals[q].x = f2bf(v.x); vals[q].y = f2bf(v.y); vals[q].z = f2bf(v.z); vals[q].w = f2bf(v.w);
    }
    if (r.p1 >= 0) {
        unsigned short* d = disp + ((size_t)r.e1 * CAPACITY + r.p1) * DMODEL;
#pragma unroll
        for (int q = 0; q < 4; ++q) *(ushort4*)(d + (q * 64 + l) * 4) = vals[q];
    }
    if (r.p2 >= 0) {
        unsigned short* d = disp + ((size_t)r.e2 * CAPACITY + r.p2) * DMODEL;
#pragma unroll
        for (int q = 0; q < 4; ++q) *(ushort4*)(d + (q * 64 + l) * 4) = vals[q];
    }
}

// ---------------- 256-wide bf16 GEMM: C[M,N] = A[M,K] * Bt[N,K]^T (+bias, opt gelu)
// BM=256, BK=64, 512 threads (8 waves, WMxWN), double-buffered LDS, counted vmcnt,
// both-sides XOR chunk swizzle (chunk ^= row&7), raw barriers, LDS-transposed epilogue.
template <int BN, int WM, int WN, int MODE>
__global__ __launch_bounds__(512, 2)
void gemm256(const unsigned short* __restrict__ A, const unsigned short* __restrict__ Bt,
             unsigned short* __restrict__ C, const float* __restrict__ bias,
             const int* __restrict__ cnt,
             int N, int K, int Ntiles,
             size_t strideAe, size_t strideBe, size_t strideCe, int biasStride) {
    constexpr int MF = 256 / WM / 16;        // m-frags per wave
    constexpr int NF = BN / WN / 16;         // n-frags per wave
    constexpr int RW = 256 / WM;             // wave rows
    constexpr int CW = BN / WN;              // wave cols (=64)
    constexpr int NBJ = BN / 64;             // B stage insts per wave
    constexpr int LPT = 4 + NBJ;             // loads per tile per wave
    constexpr int ASLOT = 256 * 64;          // ushorts per A slot
    constexpr int BSLOT = BN * 64;

    __shared__ unsigned short slds[(2 * 256 + 2 * BN) * 64];

    int e = blockIdx.z;
    int mt = blockIdx.x / Ntiles, nt = blockIdx.x % Ntiles;
    if (mt * 256 >= cnt[e]) return;
    const unsigned short* Ae = A + (size_t)e * strideAe;
    const unsigned short* Be = Bt + (size_t)e * strideBe;
    unsigned short* Ce = C + (size_t)e * strideCe;
    const float* be = bias + (size_t)e * biasStride;

    int tid = threadIdx.x;
    int wv = tid >> 6, ln = tid & 63;
    int wm = wv / WN, wn = wv % WN;
    int lr = ln & 15, kc = ln >> 4;
    int rsw = lr & 7;

    // staging addresses
    size_t gOffA[4]; int ldsA[4];
#pragma unroll
    for (int j = 0; j < 4; ++j) {
        int g = (wv * 4 + j) * 64 + ln;
        int row = g >> 3, cl = g & 7, cs = cl ^ (row & 7);
        ldsA[j] = (wv * 4 + j) * 512;
        gOffA[j] = (size_t)(mt * 256 + row) * K + cs * 8;
    }
    size_t gOffB[NBJ]; int ldsB[NBJ];
#pragma unroll
    for (int j = 0; j < NBJ; ++j) {
        int g = (wv * NBJ + j) * 64 + ln;
        int row = g >> 3, cl = g & 7, cs = cl ^ (row & 7);
        ldsB[j] = (wv * NBJ + j) * 512;
        gOffB[j] = (size_t)(nt * BN + row) * K + cs * 8;
    }
    // fragment read offsets
    int aoff[MF], boff[NF];
#pragma unroll
    for (int i = 0; i < MF; ++i) aoff[i] = (wm * RW + i * 16 + lr) * 64;
#pragma unroll
    for (int j = 0; j < NF; ++j) boff[j] = (wn * CW + j * 16 + lr) * 64;
    int chk0 = ((kc) ^ rsw) * 8;
    int chk1 = ((kc + 4) ^ rsw) * 8;

    f32x4 acc[MF][NF];
#pragma unroll
    for (int i = 0; i < MF; ++i)
#pragma unroll
        for (int j = 0; j < NF; ++j) acc[i][j] = (f32x4){0.f, 0.f, 0.f, 0.f};

    auto stage = [&](int slot, int kt) {
        unsigned short* da = slds + slot * ASLOT;
        unsigned short* db = slds + 2 * ASLOT + slot * BSLOT;
#pragma unroll
        for (int j = 0; j < 4; ++j) gload16(Ae + gOffA[j] + kt * 64, da + ldsA[j]);
#pragma unroll
        for (int j = 0; j < NBJ; ++j) gload16(Be + gOffB[j] + kt * 64, db + ldsB[j]);
    };

    int nk = K >> 6;
    stage(0, 0);
    stage(1, 1);
    wait_vmcnt<LPT>();
    __builtin_amdgcn_s_barrier();

    int cur = 0;
    for (int kt = 0; kt < nk; ++kt) {
        const unsigned short* sa = slds + cur * ASLOT;
        const unsigned short* sb = slds + 2 * ASLOT + cur * BSLOT;
        __builtin_amdgcn_s_setprio(1);
#pragma unroll
        for (int s = 0; s < 2; ++s) {
            int ck = (s == 0) ? chk0 : chk1;
            bf16x8 av[MF], bv[NF];
#pragma unroll
            for (int i = 0; i < MF; ++i) av[i] = *(const bf16x8*)(sa + aoff[i] + ck);
#pragma unroll
            for (int j = 0; j < NF; ++j) bv[j] = *(const bf16x8*)(sb + boff[j] + ck);
#pragma unroll
            for (int i = 0; i < MF; ++i)
#pragma unroll
                for (int j = 0; j < NF; ++j)
                    acc[i][j] = __builtin_amdgcn_mfma_f32_16x16x32_bf16(av[i], bv[j], acc[i][j], 0, 0, 0);
        }
        __builtin_amdgcn_s_setprio(0);
        __builtin_amdgcn_sched_barrier(0);
        __builtin_amdgcn_s_barrier();                 // all waves done reading cur
        if (kt + 2 < nk) stage(cur, kt + 2);          // refill cur with tile kt+2
        if (kt + 1 < nk) {
            if (kt + 2 < nk) wait_vmcnt<LPT>(); else wait_vmcnt<0>();
            __builtin_amdgcn_s_barrier();             // tile kt+1 visible everywhere
        }
        cur ^= 1;
    }

    // epilogue: stage through LDS for coalesced 16B stores
    __syncthreads();
    unsigned short* scratch = slds + wv * (RW * CW);
    float bvj[NF];
#pragma unroll
    for (int j = 0; j < NF; ++j) bvj[j] = be[nt * BN + wn * CW + j * 16 + lr];
#pragma unroll
    for (int i = 0; i < MF; ++i) {
#pragma unroll
        for (int j = 0; j < NF; ++j) {
            int col_l = j * 16 + lr;
#pragma unroll
            for (int r = 0; r < 4; ++r) {
                int row_l = i * 16 + kc * 4 + r;
                float v = acc[i][j][r] + bvj[j];
                if (MODE == 0) v = gelu_f(v);
                scratch[row_l * CW + col_l] = f2bf(v);
            }
        }
    }
    int rrow = ln >> 3, rcol = (ln & 7) * 8;
#pragma unroll
    for (int p = 0; p < RW / 8; ++p) {
        int row_l = p * 8 + rrow;
        ushort8v v = *(const ushort8v*)&scratch[row_l * CW + rcol];
        int row_g = mt * 256 + wm * RW + row_l;
        int col_g = nt * BN + wn * CW + rcol;
        *(ushort8v*)&Ce[(size_t)row_g * N + col_g] = v;
    }
}

// ---------------- combine: out[s] = w1*eout[e1,p1] + w2*eout[e2,p2]
__global__ void combine_kernel(const TokenRoute* __restrict__ route, const unsigned short* __restrict__ eout,
                               float* __restrict__ out) {
    int s = blockIdx.x, l = threadIdx.x;
    TokenRoute r = route[s];
    bool v1 = r.p1 >= 0, v2 = r.p2 >= 0;
#pragma unroll
    for (int q = 0; q < 4; ++q) {
        int i = (q * 64 + l) * 4;
        float4 a = {0.f, 0.f, 0.f, 0.f};
        if (v1) {
            const unsigned short* p = eout + ((size_t)r.e1 * CAPACITY + r.p1) * DMODEL + i;
            ushort4 u = *(const ushort4*)p;
            a.x += r.w1 * bf2f(u.x); a.y += r.w1 * bf2f(u.y);
            a.z += r.w1 * bf2f(u.z); a.w += r.w1 * bf2f(u.w);
        }
        if (v2) {
            const unsigned short* p = eout + ((size_t)r.e2 * CAPACITY + r.p2) * DMODEL + i;
            ushort4 u = *(const ushort4*)p;
            a.x += r.w2 * bf2f(u.x); a.y += r.w2 * bf2f(u.y);
            a.z += r.w2 * bf2f(u.z); a.w += r.w2 * bf2f(u.w);
        }
        *(float4*)(out + (size_t)s * DMODEL + i) = a;
    }
}

extern "C" void kernel_launch(void* const* d_in, const int* in_sizes, int n_in,
                              void* d_out, int out_size, void* d_ws, size_t ws_size,
                              hipStream_t stream) {
    const float* inputs = (const float*)d_in[0];
    const float* gw     = (const float*)d_in[1];
    const float* w1     = (const float*)d_in[2];
    const float* b1     = (const float*)d_in[3];
    const float* w2     = (const float*)d_in[4];
    const float* b2     = (const float*)d_in[5];
    float* out = (float*)d_out;

    char* ws = (char*)d_ws;
    const size_t SZ_W = (size_t)NEXP * DMODEL * HDIM * 2;           // 64 MiB each
    const size_t SZ_DISP = (size_t)NEXP * CAPACITY * DMODEL * 2;    // 20 MiB
    const size_t SZ_H = (size_t)NEXP * CAPACITY * HDIM * 2;         // 80 MiB
    unsigned short* wb1t = (unsigned short*)(ws);
    unsigned short* wb2t = (unsigned short*)(ws + SZ_W);
    unsigned short* disp = (unsigned short*)(ws + 2 * SZ_W);        // aliased: eout after GEMM2
    unsigned short* h    = (unsigned short*)(ws + 2 * SZ_W + SZ_DISP);
    float* gates = (float*)(ws + 2 * SZ_W + SZ_DISP + SZ_H);
    TokenRoute* route = (TokenRoute*)(ws + 2 * SZ_W + SZ_DISP + SZ_H + (size_t)S_TOK * NEXP * 4);
    int* cnt = (int*)((char*)route + (size_t)S_TOK * sizeof(TokenRoute));

    // w1 [E][D][H] -> wb1t [E][H][D]; w2 [E][H][D] -> wb2t [E][D][H]
    transpose_cvt<<<dim3(HDIM / 64, DMODEL / 64, NEXP), 256, 0, stream>>>(w1, wb1t, DMODEL, HDIM);
    transpose_cvt<<<dim3(DMODEL / 64, HDIM / 64, NEXP), 256, 0, stream>>>(w2, wb2t, HDIM, DMODEL);
    gate_kernel<<<S_TOK, 64, 0, stream>>>(inputs, gw, gates, route);
    route_scan<<<1, 1024, 0, stream>>>(route, gates, cnt, out + (size_t)S_TOK * DMODEL);
    dispatch_scatter<<<S_TOK, 64, 0, stream>>>(inputs, route, disp);
    // GEMM1: h = gelu(disp @ w1t^T + b1)   M=1280 N=4096 K=1024, BN=256, waves 2x4
    gemm256<256, 2, 4, 0><<<dim3((CAPACITY / 256 + 1) * (HDIM / 256), 1, NEXP), 512, 0, stream>>>(
        disp, wb1t, h, b1, cnt, HDIM, DMODEL, HDIM / 256,
        (size_t)CAPACITY * DMODEL, (size_t)HDIM * DMODEL, (size_t)CAPACITY * HDIM, HDIM);
    // GEMM2: eout = h @ w2t^T + b2         M=1280 N=1024 K=4096, BN=128, waves 4x2
    gemm256<128, 4, 2, 1><<<dim3((CAPACITY / 256 + 1) * (DMODEL / 128), 1, NEXP), 512, 0, stream>>>(
        h, wb2t, disp, b2, cnt, DMODEL, HDIM, DMODEL / 128,
        (size_t)CAPACITY * HDIM, (size_t)DMODEL * HDIM, (size_t)CAPACITY * DMODEL, DMODEL);
    combine_kernel<<<S_TOK, 64, 0, stream>>>(route, disp, out);
}

// Round 4
// 582.212 us; speedup vs baseline: 1.1035x; 1.1035x over previous
//
#include <hip/hip_runtime.h>

#define S_TOK 4096
#define DMODEL 1024
#define HDIM 4096
#define NEXP 8
#define CAPACITY 1280

struct TokenRoute { int e1, p1, e2, p2; float w1, w2; };

typedef __bf16 bf16x8 __attribute__((ext_vector_type(8)));
typedef float f32x4 __attribute__((ext_vector_type(4)));
typedef unsigned short ushort8v __attribute__((ext_vector_type(8)));

__device__ __forceinline__ unsigned short f2bf(float f) {
    unsigned int u = __float_as_uint(f);
    unsigned int r = 0x7fffu + ((u >> 16) & 1u);
    return (unsigned short)((u + r) >> 16);
}
__device__ __forceinline__ float bf2f(unsigned short b) {
    return __uint_as_float(((unsigned int)b) << 16);
}

__device__ __forceinline__ void gload16(const void* gsrc, void* ldst) {
    __builtin_amdgcn_global_load_lds(
        (const __attribute__((address_space(1))) unsigned int*)gsrc,
        (__attribute__((address_space(3))) unsigned int*)ldst, 16, 0, 0);
}

template <int N> __device__ __forceinline__ void wait_vmcnt() {
    if constexpr (N == 0) asm volatile("s_waitcnt vmcnt(0)" ::: "memory");
    else if constexpr (N == 6) asm volatile("s_waitcnt vmcnt(6)" ::: "memory");
}

__device__ __forceinline__ float gelu_f(float x) {
    float u = x * (0.7978845608028654f + 0.0356774081363f * x * x);
    return x / (1.0f + __expf(-2.0f * u));   // == 0.5x(1+tanh(u))
}

// ---------------- transpose + fp32->bf16: src [E][R][C] f32 -> dst [E][C][R] bf16
// 4x4 micro-block transpose in registers; vectorized LDS on both sides.
__global__ __launch_bounds__(256) void transpose_cvt(const float* __restrict__ src,
                                                     unsigned short* __restrict__ dst,
                                                     int R, int C) {
    __shared__ unsigned short t2[64][72];   // 144B stride: 16B-aligned rows
    size_t eoff = (size_t)blockIdx.z * R * C;
    int r0 = blockIdx.y * 64, c0 = blockIdx.x * 64, tid = threadIdx.x;
    int q = tid & 15, g = tid >> 4;
    float vr[4][4];
#pragma unroll
    for (int rr = 0; rr < 4; ++rr) {
        float4 v = *(const float4*)(src + eoff + (size_t)(r0 + g * 4 + rr) * C + c0 + q * 4);
        vr[rr][0] = v.x; vr[rr][1] = v.y; vr[rr][2] = v.z; vr[rr][3] = v.w;
    }
#pragma unroll
    for (int cc = 0; cc < 4; ++cc) {
        ushort4 o;
        o.x = f2bf(vr[0][cc]); o.y = f2bf(vr[1][cc]);
        o.z = f2bf(vr[2][cc]); o.w = f2bf(vr[3][cc]);
        *(ushort4*)&t2[q * 4 + cc][g * 4] = o;
    }
    __syncthreads();
    int orr = tid >> 2, seg = tid & 3;
    ushort8v a = *(const ushort8v*)&t2[orr][seg * 16];
    ushort8v b = *(const ushort8v*)&t2[orr][seg * 16 + 8];
    unsigned short* dp = dst + eoff + (size_t)(c0 + orr) * R + r0 + seg * 16;
    *(ushort8v*)dp = a;
    *(ushort8v*)(dp + 8) = b;
}

// ---------------- gating + token fp32->bf16 convert. One wave per token, 4 tokens/block.
__global__ __launch_bounds__(256)
void gate_cvt(const float* __restrict__ tokens, const float* __restrict__ gw,
              unsigned short* __restrict__ tok, float* __restrict__ gates,
              TokenRoute* __restrict__ route) {
    int wv = threadIdx.x >> 6, l = threadIdx.x & 63;
    int s = blockIdx.x * 4 + wv;
    const float* x = tokens + (size_t)s * DMODEL;
    float p[NEXP];
#pragma unroll
    for (int e = 0; e < NEXP; ++e) p[e] = 0.f;
#pragma unroll
    for (int it = 0; it < 4; ++it) {
        int i = (it * 64 + l) * 4;
        float4 v = *(const float4*)(x + i);
        ushort4 o; o.x = f2bf(v.x); o.y = f2bf(v.y); o.z = f2bf(v.z); o.w = f2bf(v.w);
        *(ushort4*)(tok + (size_t)s * DMODEL + i) = o;
#pragma unroll
        for (int e = 0; e < NEXP; ++e) {
            float4 gg = *(const float4*)(gw + e * DMODEL + i);
            p[e] += v.x * gg.x + v.y * gg.y + v.z * gg.z + v.w * gg.w;
        }
    }
#pragma unroll
    for (int e = 0; e < NEXP; ++e) {
        float v = p[e];
        v += __shfl_xor(v, 32); v += __shfl_xor(v, 16); v += __shfl_xor(v, 8);
        v += __shfl_xor(v, 4);  v += __shfl_xor(v, 2);  v += __shfl_xor(v, 1);
        p[e] = v;
    }
    int e1 = 0; float b1v = p[0];
#pragma unroll
    for (int e = 1; e < NEXP; ++e) if (p[e] > b1v) { b1v = p[e]; e1 = e; }
    int e2 = -1; float b2v = -3.0e38f;
#pragma unroll
    for (int e = 0; e < NEXP; ++e) if (e != e1 && p[e] > b2v) { b2v = p[e]; e2 = e; }
    float mx = p[0];
#pragma unroll
    for (int e = 1; e < NEXP; ++e) mx = fmaxf(mx, p[e]);
    float sum = 0.f;
#pragma unroll
    for (int e = 0; e < NEXP; ++e) { p[e] = __expf(p[e] - mx); sum += p[e]; }
    float inv = 1.0f / sum;
#pragma unroll
    for (int e = 0; e < NEXP; ++e) p[e] *= inv;
    float g1 = __expf(b1v - mx) * inv;
    float g2 = __expf(b2v - mx) * inv;
    if (l == 0) {
        float* gp = gates + (size_t)s * NEXP;
#pragma unroll
        for (int e = 0; e < NEXP; ++e) gp[e] = p[e];
        TokenRoute r; r.e1 = e1; r.p1 = 0; r.e2 = e2; r.p2 = 0; r.w1 = g1; r.w2 = g2;
        route[s] = r;
    }
}

// ---------------- routing scan (hierarchical, packed 8x16-bit counters in 2x u64)
__device__ __forceinline__ unsigned ext16(unsigned long long lo, unsigned long long hi, int e) {
    unsigned long long q = (e < 4) ? lo : hi;
    return (unsigned)((q >> ((e & 3) * 16)) & 0xFFFFULL);
}

__global__ __launch_bounds__(1024)
void route_scan(TokenRoute* __restrict__ route, const float* __restrict__ gates,
                int* __restrict__ cnt, float* __restrict__ laux_out) {
    __shared__ unsigned long long wt[16][4];
    __shared__ float fsum[16][NEXP];
    int t = threadIdx.x, wid = t >> 6, ln = t & 63;
    TokenRoute tr[4];
    unsigned long long own[4] = {0, 0, 0, 0};
#pragma unroll
    for (int j = 0; j < 4; ++j) {
        tr[j] = route[t * 4 + j];
        int e1 = tr[j].e1, e2 = tr[j].e2;
        if (e1 < 4) own[0] += 1ULL << (e1 * 16); else own[1] += 1ULL << ((e1 - 4) * 16);
        if (e2 < 4) own[2] += 1ULL << (e2 * 16); else own[3] += 1ULL << ((e2 - 4) * 16);
    }
    unsigned long long inc[4] = {own[0], own[1], own[2], own[3]};
#pragma unroll
    for (int off = 1; off < 64; off <<= 1) {
#pragma unroll
        for (int q = 0; q < 4; ++q) {
            unsigned long long v = __shfl_up(inc[q], off);
            if (ln >= off) inc[q] += v;
        }
    }
    if (ln == 63) {
#pragma unroll
        for (int q = 0; q < 4; ++q) wt[wid][q] = inc[q];
    }
    __syncthreads();
    unsigned long long woff[4] = {0, 0, 0, 0}, tot[4] = {0, 0, 0, 0};
    for (int w = 0; w < 16; ++w) {
#pragma unroll
        for (int q = 0; q < 4; ++q) {
            unsigned long long v = wt[w][q];
            tot[q] += v;
            if (w < wid) woff[q] += v;
        }
    }
    unsigned long long ex[4];
#pragma unroll
    for (int q = 0; q < 4; ++q) ex[q] = woff[q] + inc[q] - own[q];

    float gs[NEXP];
#pragma unroll
    for (int e = 0; e < NEXP; ++e) gs[e] = 0.f;
#pragma unroll
    for (int j = 0; j < 4; ++j) {
        const float* gp = gates + (size_t)(t * 4 + j) * NEXP;
#pragma unroll
        for (int e = 0; e < NEXP; ++e) gs[e] += gp[e];
    }
#pragma unroll
    for (int e = 0; e < NEXP; ++e) {
        float v = gs[e];
        v += __shfl_xor(v, 32); v += __shfl_xor(v, 16); v += __shfl_xor(v, 8);
        v += __shfl_xor(v, 4);  v += __shfl_xor(v, 2);  v += __shfl_xor(v, 1);
        gs[e] = v;
    }
    if (ln == 0) {
#pragma unroll
        for (int e = 0; e < NEXP; ++e) fsum[wid][e] = gs[e];
    }
    __syncthreads();
    if (t == 0) {
        float laux = 0.f;
#pragma unroll
        for (int e = 0; e < NEXP; ++e) {
            float m = 0.f;
            for (int w = 0; w < 16; ++w) m += fsum[w][e];
            unsigned t1 = ext16(tot[0], tot[1], e);
            unsigned t2 = ext16(tot[2], tot[3], e);
            laux += (m / (float)S_TOK) * ((float)t1 / (float)S_TOK);
            int c = (int)(t1 + t2);
            cnt[e] = c < CAPACITY ? c : CAPACITY;
        }
        *laux_out = laux * (float)NEXP;
    }
    unsigned long long r1lo = ex[0], r1hi = ex[1], r2lo = ex[2], r2hi = ex[3];
#pragma unroll
    for (int j = 0; j < 4; ++j) {
        int e1 = tr[j].e1, e2 = tr[j].e2;
        unsigned loc1 = ext16(r1lo, r1hi, e1);
        if (e1 < 4) r1lo += 1ULL << (e1 * 16); else r1hi += 1ULL << ((e1 - 4) * 16);
        unsigned loc2 = ext16(r2lo, r2hi, e2) + ext16(tot[0], tot[1], e2);
        if (e2 < 4) r2lo += 1ULL << (e2 * 16); else r2hi += 1ULL << ((e2 - 4) * 16);
        bool k1 = loc1 < CAPACITY, k2 = loc2 < CAPACITY;
        float G1 = k1 ? tr[j].w1 : 0.f;
        float G2 = k2 ? tr[j].w2 : 0.f;
        float denom = fmaxf(G1 + G2, 1.1920929e-07f);
        TokenRoute r;
        r.e1 = e1; r.p1 = k1 ? (int)loc1 : -1;
        r.e2 = e2; r.p2 = k2 ? (int)loc2 : -1;
        r.w1 = G1 / denom; r.w2 = G2 / denom;
        route[t * 4 + j] = r;
    }
}

// ---------------- idx scatter: idx[e][pos] = token id
__global__ void idx_fill(const TokenRoute* __restrict__ route, int* __restrict__ idx) {
    int s = blockIdx.x * 256 + threadIdx.x;
    TokenRoute r = route[s];
    if (r.p1 >= 0) idx[r.e1 * CAPACITY + r.p1] = s;
    if (r.p2 >= 0) idx[r.e2 * CAPACITY + r.p2] = s;
}

// ---------------- FFN GEMM: C[M=256-tile, N] = A[M,K] * Bt[N,K]^T (+bias, opt gelu)
// BM=256, BN=128, BK=32. 256 threads, 4 waves (2x2), wave-tile 128x64 (MF=8, NF=4).
// Triple-buffered A and B LDS slots (72 KB -> 2 blocks/CU). One barrier + one counted
// vmcnt(6) per K-iter, 2-tile stage lookahead. Pair-row XOR swizzle:
//   chunk (r,kc) stored in 128B line l=r>>1 at c = ((r&1)*4+kc) ^ (l&7).
template <int KEL, int NT, bool GATHER, int MODE>
__global__ __launch_bounds__(256, 2)
void gemm_ff(const unsigned short* __restrict__ A, const int* __restrict__ idx,
             const unsigned short* __restrict__ B, unsigned short* __restrict__ C,
             const float* __restrict__ bias, const int* __restrict__ cnt,
             int N, size_t strideAe, size_t strideBe, size_t strideCe, int biasStride) {
    constexpr int NK = KEL / 32;
    __shared__ unsigned short slds[3 * 8192 + 3 * 4096];   // A slots | B slots (73728 B)

    constexpr int TOTAL = NEXP * 5 * NT;
    int bid = blockIdx.x;
    int nb = (bid & 7) * (TOTAL >> 3) + (bid >> 3);        // XCD-chunked (TOTAL%8==0)
    int nt = nb % NT; int mt = (nb / NT) % 5; int e = nb / (NT * 5);
    if (mt * 256 >= cnt[e]) return;

    const unsigned short* Ae = GATHER ? A : (A + (size_t)e * strideAe);
    const unsigned short* Be = B + (size_t)e * strideBe + (size_t)nt * 128 * KEL;
    unsigned short* Ce = C + (size_t)e * strideCe;
    const float* be = bias + (size_t)e * biasStride;

    int tid = threadIdx.x, wv = tid >> 6, ln = tid & 63;
    int wm = wv >> 1, wn = wv & 1;
    int lr = ln & 15, kc4 = ln >> 4;

    // ---- stage address precompute
    const unsigned short* gAp[4]; int ldsA[4];
#pragma unroll
    for (int jj = 0; jj < 4; ++jj) {
        int p = (wv * 4 + jj) * 64 + ln;
        int lq = p >> 3, c = p & 7, u = c ^ (lq & 7);
        int r = 2 * lq + (u >> 2), kcs = u & 3;
        ldsA[jj] = p * 8;
        if constexpr (GATHER) {
            int tokr = idx[e * CAPACITY + mt * 256 + r] & (S_TOK - 1);  // poison-safe clamp
            gAp[jj] = Ae + (size_t)tokr * KEL + kcs * 8;
        } else {
            gAp[jj] = Ae + (size_t)(mt * 256 + r) * KEL + kcs * 8;
        }
    }
    const unsigned short* gBp[2]; int ldsB[2];
#pragma unroll
    for (int jj = 0; jj < 2; ++jj) {
        int p = (wv * 2 + jj) * 64 + ln;
        int lq = p >> 3, c = p & 7, u = c ^ (lq & 7);
        int r = 2 * lq + (u >> 2), kcs = u & 3;
        ldsB[jj] = p * 8;
        gBp[jj] = Be + (size_t)r * KEL + kcs * 8;
    }
    // ---- fragment read offsets (ushort idx within slot)
    int aoff[8], boff[4];
#pragma unroll
    for (int i = 0; i < 8; ++i) {
        int row = wm * 128 + i * 16 + lr;
        int lq = row >> 1, c = (((lr & 1) << 2) | kc4) ^ (lq & 7);
        aoff[i] = lq * 64 + c * 8;
    }
#pragma unroll
    for (int j = 0; j < 4; ++j) {
        int row = wn * 64 + j * 16 + lr;
        int lq = row >> 1, c = (((lr & 1) << 2) | kc4) ^ (lq & 7);
        boff[j] = lq * 64 + c * 8;
    }

    f32x4 acc[8][4];
#pragma unroll
    for (int i = 0; i < 8; ++i)
#pragma unroll
        for (int j = 0; j < 4; ++j) acc[i][j] = (f32x4){0.f, 0.f, 0.f, 0.f};

    auto stage = [&](int kt, int slot) {
#pragma unroll
        for (int jj = 0; jj < 4; ++jj)
            gload16(gAp[jj] + kt * 32, &slds[slot * 8192 + ldsA[jj]]);
#pragma unroll
        for (int jj = 0; jj < 2; ++jj)
            gload16(gBp[jj] + kt * 32, &slds[24576 + slot * 4096 + ldsB[jj]]);
    };

    stage(0, 0);
    stage(1, 1);
    wait_vmcnt<6>();                       // confirm tile 0 (A0:4 + B0:2 oldest of 12)
    __builtin_amdgcn_s_barrier();

    int sc = 0;
    for (int kt = 0; kt < NK; ++kt) {
        int s2 = sc + 2; if (s2 >= 3) s2 -= 3;
        if (kt + 2 < NK) stage(kt + 2, s2);   // writes slot last read at iter kt-1 (barrier-gated)
        bf16x8 av[8], bv[4];
#pragma unroll
        for (int i = 0; i < 8; ++i) av[i] = *(const bf16x8*)&slds[sc * 8192 + aoff[i]];
#pragma unroll
        for (int j = 0; j < 4; ++j) bv[j] = *(const bf16x8*)&slds[24576 + sc * 4096 + boff[j]];
        __builtin_amdgcn_s_setprio(1);
#pragma unroll
        for (int i = 0; i < 8; ++i)
#pragma unroll
            for (int j = 0; j < 4; ++j)
                acc[i][j] = __builtin_amdgcn_mfma_f32_16x16x32_bf16(av[i], bv[j], acc[i][j], 0, 0, 0);
        __builtin_amdgcn_s_setprio(0);
        if (kt + 2 < NK) wait_vmcnt<6>();    // confirm tile kt+1 (leaves the 6 just-issued)
        else wait_vmcnt<0>();
        __builtin_amdgcn_s_barrier();
        sc = (sc == 2) ? 0 : sc + 1;
    }

    // ---- epilogue: bias (+gelu) -> bf16, LDS transpose for 16B coalesced stores
    __syncthreads();
    unsigned short* scratch = slds + wv * 8192;   // 128x64 ushorts per wave
    float bvj[4];
#pragma unroll
    for (int j = 0; j < 4; ++j) bvj[j] = be[nt * 128 + wn * 64 + j * 16 + lr];
#pragma unroll
    for (int i = 0; i < 8; ++i) {
#pragma unroll
        for (int j = 0; j < 4; ++j) {
#pragma unroll
            for (int r = 0; r < 4; ++r) {
                float vv = acc[i][j][r] + bvj[j];
                if (MODE == 0) vv = gelu_f(vv);
                scratch[(i * 16 + kc4 * 4 + r) * 64 + j * 16 + lr] = f2bf(vv);
            }
        }
    }
    __syncthreads();
    int rrow = ln >> 3, rcol = (ln & 7) * 8;
#pragma unroll
    for (int p = 0; p < 16; ++p) {
        int row_l = p * 8 + rrow;
        ushort8v v = *(const ushort8v*)&scratch[row_l * 64 + rcol];
        int row_g = mt * 256 + wm * 128 + row_l;
        int col_g = nt * 128 + wn * 64 + rcol;
        *(ushort8v*)&Ce[(size_t)row_g * N + col_g] = v;
    }
}

// ---------------- combine: out[s] = w1*eout[e1,p1] + w2*eout[e2,p2]
__global__ void combine_kernel(const TokenRoute* __restrict__ route, const unsigned short* __restrict__ eout,
                               float* __restrict__ out) {
    int s = blockIdx.x, l = threadIdx.x;
    TokenRoute r = route[s];
    bool v1 = r.p1 >= 0, v2 = r.p2 >= 0;
#pragma unroll
    for (int q = 0; q < 4; ++q) {
        int i = (q * 64 + l) * 4;
        float4 a = {0.f, 0.f, 0.f, 0.f};
        if (v1) {
            const unsigned short* p = eout + ((size_t)r.e1 * CAPACITY + r.p1) * DMODEL + i;
            ushort4 u = *(const ushort4*)p;
            a.x += r.w1 * bf2f(u.x); a.y += r.w1 * bf2f(u.y);
            a.z += r.w1 * bf2f(u.z); a.w += r.w1 * bf2f(u.w);
        }
        if (v2) {
            const unsigned short* p = eout + ((size_t)r.e2 * CAPACITY + r.p2) * DMODEL + i;
            ushort4 u = *(const ushort4*)p;
            a.x += r.w2 * bf2f(u.x); a.y += r.w2 * bf2f(u.y);
            a.z += r.w2 * bf2f(u.z); a.w += r.w2 * bf2f(u.w);
        }
        *(float4*)(out + (size_t)s * DMODEL + i) = a;
    }
}

extern "C" void kernel_launch(void* const* d_in, const int* in_sizes, int n_in,
                              void* d_out, int out_size, void* d_ws, size_t ws_size,
                              hipStream_t stream) {
    const float* inputs = (const float*)d_in[0];
    const float* gw     = (const float*)d_in[1];
    const float* w1     = (const float*)d_in[2];
    const float* b1     = (const float*)d_in[3];
    const float* w2     = (const float*)d_in[4];
    const float* b2     = (const float*)d_in[5];
    float* out = (float*)d_out;

    char* ws = (char*)d_ws;
    const size_t SZ_W   = (size_t)NEXP * DMODEL * HDIM * 2;        // 64 MiB
    const size_t SZ_H   = (size_t)NEXP * CAPACITY * HDIM * 2;      // 80 MiB
    const size_t SZ_TOK = (size_t)S_TOK * DMODEL * 2;              // 8 MiB
    unsigned short* wb1t = (unsigned short*)(ws);                  // GEMM1 B; dead after GEMM1
    unsigned short* wb2t = (unsigned short*)(ws + SZ_W);
    unsigned short* h    = (unsigned short*)(ws + 2 * SZ_W);
    unsigned short* tok  = (unsigned short*)(ws + 2 * SZ_W + SZ_H);
    float* gates = (float*)(ws + 2 * SZ_W + SZ_H + SZ_TOK);
    TokenRoute* route = (TokenRoute*)((char*)gates + (size_t)S_TOK * NEXP * 4);
    int* cnt = (int*)((char*)route + (size_t)S_TOK * sizeof(TokenRoute));
    int* idxb = (int*)((char*)cnt + 128);
    unsigned short* eout = wb1t;                                   // 20 MiB alias over dead wb1t

    // w1 [E][D][H] -> wb1t [E][H][D]; w2 [E][H][D] -> wb2t [E][D][H]
    transpose_cvt<<<dim3(HDIM / 64, DMODEL / 64, NEXP), 256, 0, stream>>>(w1, wb1t, DMODEL, HDIM);
    transpose_cvt<<<dim3(DMODEL / 64, HDIM / 64, NEXP), 256, 0, stream>>>(w2, wb2t, HDIM, DMODEL);
    gate_cvt<<<S_TOK / 4, 256, 0, stream>>>(inputs, gw, tok, gates, route);
    route_scan<<<1, 1024, 0, stream>>>(route, gates, cnt, out + (size_t)S_TOK * DMODEL);
    idx_fill<<<S_TOK / 256, 256, 0, stream>>>(route, idxb);
    // GEMM1: h = gelu(gather(tok) @ w1t^T + b1)   M<=1280 N=4096 K=1024; 1280 blocks
    gemm_ff<DMODEL, 32, true, 0><<<NEXP * 5 * 32, 256, 0, stream>>>(
        tok, idxb, wb1t, h, b1, cnt, HDIM,
        0, (size_t)HDIM * DMODEL, (size_t)CAPACITY * HDIM, HDIM);
    // GEMM2: eout = h @ w2t^T + b2                M<=1280 N=1024 K=4096; 320 blocks
    gemm_ff<HDIM, 8, false, 1><<<NEXP * 5 * 8, 256, 0, stream>>>(
        h, idxb, wb2t, eout, b2, cnt, DMODEL,
        (size_t)CAPACITY * HDIM, (size_t)DMODEL * HDIM, (size_t)CAPACITY * DMODEL, DMODEL);
    combine_kernel<<<S_TOK, 64, 0, stream>>>(route, eout, out);
}